// Round 13
// baseline (194.855 us; speedup 1.0000x reference)
//
#include <hip/hip_runtime.h>
#include <hip/hip_bf16.h>

#define NB 1024
#define SS 256
#define LL 256
#define HH 128
#define KMAX 16
#define KE 8

typedef __attribute__((ext_vector_type(8))) short bf16x8;
typedef __attribute__((ext_vector_type(4))) float f32x4;
typedef unsigned short u16;
typedef unsigned int u32;

__device__ __forceinline__ void split_bf16(float a, u16& hi, u16& lo) {
  u32 u = __float_as_uint(a);
  u32 hb = (u + 0x8000u) & 0xFFFF0000u;      // RTN-ish bf16 hi
  float lf = a - __uint_as_float(hb);        // exact residual
  hi = (u16)(hb >> 16);
  lo = (u16)(__float_as_uint(lf) >> 16);
}

// ---- prep: W[l][h] -> Wt_hi[h][l], Wt_lo[h][l] (bf16 split, transposed) ----
__global__ __launch_bounds__(256) void prep_w(
    const float* __restrict__ Wm, u16* __restrict__ wt_hi, u16* __restrict__ wt_lo) {
  const int id = blockIdx.x * 256 + threadIdx.x;
  const int h = id & 127, ll = id >> 7;
  const float a = Wm[(size_t)ll * HH + h];
  u16 hi, lo;
  split_bf16(a, hi, lo);
  wt_hi[h * LL + ll] = hi;
  wt_lo[h * LL + ll] = lo;
}

// ============ Fused kernel, low kept in MFMA accumulator registers ==========
// acc[mt][nt][j] = low[w*32+mt*16+lk*4+j][nt*16+lr]  (verified C/D mapping)
// LDS: 61440 B union { GEMM staging | routing arrays } -> 2 blocks/CU.
// __launch_bounds__(512, 2): VGPR cap 128 under either launch-bounds
// semantics (R10's (512,4) gave cap 64 -> acc spill -> 413us regression).
#define LDSB 61440

__global__ __launch_bounds__(512, 2) void capsule_reg(
    const float* __restrict__ inputs, const int* __restrict__ seq_len,
    const u16* __restrict__ wt_hi, const u16* __restrict__ wt_lo,
    const float* __restrict__ r_init, float* __restrict__ out) {
  __shared__ __align__(16) char smem[LDSB];
  // GEMM-phase staging views (dead after last MFMA barrier)
  u16* Ahi = (u16*)smem;                   // [256][40] = 20480
  u16* Alo = (u16*)(smem + 20480);         // 20480
  u16* Bhs = (u16*)(smem + 40960);         // [128][40] = 10240
  u16* Bls = (u16*)(smem + 51200);         // 10240
  // routing-phase views (live after GEMM)
  float (*s_p)[12]        = (float(*)[12])smem;                  // [256][12] 12288
  float (*s_partT)[128][8] = (float(*)[128][8])(smem + 12288);   // [8][128][8] 32768
  float (*s_highT)[8]     = (float(*)[8])(smem + 45056);         // [128][8] 4096
  float* s_inv            = (float*)(smem + 49152);              // [256] 1024
  float* s_scale          = (float*)(smem + 50176);              // [8]

  const int b = blockIdx.x, t = threadIdx.x, sl = seq_len[b];
  const int w = t >> 6, l = t & 63, lr = l & 15, lk = l >> 4;

  const int ilog = 31 - __clz(sl);
  float nhf = ((sl & (sl - 1)) == 0) ? (float)ilog : log2f((float)sl);
  nhf = fmaxf(1.0f, fminf(16.0f, nhf));
  const int ka = (int)ceilf(nhf);

  // prefetch r_init slice (consumed post-GEMM; latency hidden under GEMM)
  const float4 rpre = *(const float4*)(r_init + ((size_t)b * SS + (t >> 1)) * KMAX + (t & 1) * 4);

  // ---------------- GEMM phase ----------------
  f32x4 acc[2][8];
  #pragma unroll
  for (int mt = 0; mt < 2; ++mt)
    #pragma unroll
    for (int nt = 0; nt < 8; ++nt) acc[mt][nt] = (f32x4){0.f, 0.f, 0.f, 0.f};

  const float* Ab = inputs + (size_t)b * SS * LL;
  const int arow = t >> 3, aq = t & 7;
  const int bcol = t >> 2, bpart = t & 3;
  const bool wave_active = (w * 32) < sl;

  float4 pre0, pre1, pre2, pre3;
  uint4 pbh, pbl;
  {
    if (arow < sl)        pre0 = *(const float4*)(Ab + (size_t)arow * LL + aq * 4);
    if (arow + 64 < sl)   pre1 = *(const float4*)(Ab + (size_t)(arow + 64) * LL + aq * 4);
    if (arow + 128 < sl)  pre2 = *(const float4*)(Ab + (size_t)(arow + 128) * LL + aq * 4);
    if (arow + 192 < sl)  pre3 = *(const float4*)(Ab + (size_t)(arow + 192) * LL + aq * 4);
    pbh = *(const uint4*)(wt_hi + (size_t)bcol * LL + bpart * 8);
    pbl = *(const uint4*)(wt_lo + (size_t)bcol * LL + bpart * 8);
  }

  for (int kc = 0; kc < LL; kc += 32) {
    #pragma unroll
    for (int m = 0; m < 4; ++m) {
      const int row = arow + m * 64;
      const float4 v = (m == 0) ? pre0 : (m == 1) ? pre1 : (m == 2) ? pre2 : pre3;
      if (row < sl) {
        u16 h0,h1,h2,h3, l0,l1,l2,l3;
        split_bf16(v.x, h0, l0); split_bf16(v.y, h1, l1);
        split_bf16(v.z, h2, l2); split_bf16(v.w, h3, l3);
        uint2 hp, lp;
        hp.x = (u32)h0 | ((u32)h1 << 16);  hp.y = (u32)h2 | ((u32)h3 << 16);
        lp.x = (u32)l0 | ((u32)l1 << 16);  lp.y = (u32)l2 | ((u32)l3 << 16);
        *(uint2*)&Ahi[row * 40 + aq * 4] = hp;
        *(uint2*)&Alo[row * 40 + aq * 4] = lp;
      }
    }
    *(uint4*)&Bhs[bcol * 40 + bpart * 8] = pbh;
    *(uint4*)&Bls[bcol * 40 + bpart * 8] = pbl;
    if (kc + 32 < LL) {
      const int kn = kc + 32;
      if (arow < sl)        pre0 = *(const float4*)(Ab + (size_t)arow * LL + kn + aq * 4);
      if (arow + 64 < sl)   pre1 = *(const float4*)(Ab + (size_t)(arow + 64) * LL + kn + aq * 4);
      if (arow + 128 < sl)  pre2 = *(const float4*)(Ab + (size_t)(arow + 128) * LL + kn + aq * 4);
      if (arow + 192 < sl)  pre3 = *(const float4*)(Ab + (size_t)(arow + 192) * LL + kn + aq * 4);
      pbh = *(const uint4*)(wt_hi + (size_t)bcol * LL + kn + bpart * 8);
      pbl = *(const uint4*)(wt_lo + (size_t)bcol * LL + kn + bpart * 8);
    }
    __syncthreads();

    if (wave_active) {
      bf16x8 ah[2], al[2];
      #pragma unroll
      for (int mt = 0; mt < 2; ++mt) {
        const int row = w * 32 + mt * 16 + lr;
        ah[mt] = *(const bf16x8*)&Ahi[row * 40 + lk * 8];
        al[mt] = *(const bf16x8*)&Alo[row * 40 + lk * 8];
      }
      #pragma unroll
      for (int nt = 0; nt < 8; ++nt) {
        const int col = nt * 16 + lr;
        const bf16x8 bhf = *(const bf16x8*)&Bhs[col * 40 + lk * 8];
        const bf16x8 blf = *(const bf16x8*)&Bls[col * 40 + lk * 8];
        #pragma unroll
        for (int mt = 0; mt < 2; ++mt) {
          acc[mt][nt] = __builtin_amdgcn_mfma_f32_16x16x32_bf16(ah[mt], bhf, acc[mt][nt], 0, 0, 0);
          acc[mt][nt] = __builtin_amdgcn_mfma_f32_16x16x32_bf16(ah[mt], blf, acc[mt][nt], 0, 0, 0);
          acc[mt][nt] = __builtin_amdgcn_mfma_f32_16x16x32_bf16(al[mt], bhf, acc[mt][nt], 0, 0, 0);
        }
      }
    }
    __syncthreads();   // also fences staging death before routing-array writes
  }

  // ---------------- post-GEMM: zero masked rows, init s_p, row norms --------
  #pragma unroll
  for (int mt = 0; mt < 2; ++mt)
    #pragma unroll
    for (int j = 0; j < 4; ++j) {
      const int row = w * 32 + mt * 16 + lk * 4 + j;
      if (row >= sl) {
        #pragma unroll
        for (int nt = 0; nt < 8; ++nt) acc[mt][nt][j] = 0.f;
      }
    }
  *(float4*)&s_p[t >> 1][(t & 1) * 4] = rpre;
  #pragma unroll
  for (int mt = 0; mt < 2; ++mt)
    #pragma unroll
    for (int j = 0; j < 4; ++j) {
      const int row = w * 32 + mt * 16 + lk * 4 + j;
      float n2 = 0.f;
      #pragma unroll
      for (int nt = 0; nt < 8; ++nt) {
        const float a = acc[mt][nt][j];
        n2 = fmaf(a, a, n2);
      }
      n2 += __shfl_xor(n2, 1, 64);
      n2 += __shfl_xor(n2, 2, 64);
      n2 += __shfl_xor(n2, 4, 64);
      n2 += __shfl_xor(n2, 8, 64);
      if (lr == 0) s_inv[row] = 1.0f / fmaxf(sqrtf(n2), 1e-12f);
    }
  __syncthreads();

  // ---------------- routing iterations ----------------
  for (int it = 0; it < 3; ++it) {
    // (a) masked softmax
    if (t < SS) {
      const int s = t;
      const float4 ra = *(const float4*)&s_p[s][0];
      const float4 rb = *(const float4*)&s_p[s][4];
      float m = ra.x;
      if (1 < ka) m = fmaxf(m, ra.y);
      if (2 < ka) m = fmaxf(m, ra.z);
      if (3 < ka) m = fmaxf(m, ra.w);
      if (4 < ka) m = fmaxf(m, rb.x);
      if (5 < ka) m = fmaxf(m, rb.y);
      if (6 < ka) m = fmaxf(m, rb.z);
      if (7 < ka) m = fmaxf(m, rb.w);
      const float e0 = expf(ra.x - m);
      const float e1 = (1 < ka) ? expf(ra.y - m) : 0.f;
      const float e2 = (2 < ka) ? expf(ra.z - m) : 0.f;
      const float e3 = (3 < ka) ? expf(ra.w - m) : 0.f;
      const float e4 = (4 < ka) ? expf(rb.x - m) : 0.f;
      const float e5 = (5 < ka) ? expf(rb.y - m) : 0.f;
      const float e6 = (6 < ka) ? expf(rb.z - m) : 0.f;
      const float e7 = (7 < ka) ? expf(rb.w - m) : 0.f;
      const float sum = ((e0 + e1) + (e2 + e3)) + ((e4 + e5) + (e6 + e7));
      const float rs = (s < sl) ? (1.0f / sum) : 0.f;
      *(float4*)&s_p[s][0] = make_float4(e0 * rs, e1 * rs, e2 * rs, e3 * rs);
      *(float4*)&s_p[s][4] = make_float4(e4 * rs, e5 * rs, e6 * rs, e7 * rs);
    }
    __syncthreads();

    // (b) high[k][h] = sum_s low[s][h]*p[s][k] from registers; 2 k-passes
    #pragma unroll
    for (int kh = 0; kh < 2; ++kh) {
      f32x4 part[8];
      #pragma unroll
      for (int nt = 0; nt < 8; ++nt) part[nt] = (f32x4){0.f, 0.f, 0.f, 0.f};
      #pragma unroll
      for (int mt = 0; mt < 2; ++mt)
        #pragma unroll
        for (int j = 0; j < 4; ++j) {
          const int row = w * 32 + mt * 16 + lk * 4 + j;
          const float4 p4 = *(const float4*)&s_p[row][kh * 4];
          #pragma unroll
          for (int nt = 0; nt < 8; ++nt) {
            const float a = acc[mt][nt][j];
            part[nt].x = fmaf(a, p4.x, part[nt].x);
            part[nt].y = fmaf(a, p4.y, part[nt].y);
            part[nt].z = fmaf(a, p4.z, part[nt].z);
            part[nt].w = fmaf(a, p4.w, part[nt].w);
          }
        }
      #pragma unroll
      for (int nt = 0; nt < 8; ++nt)
        #pragma unroll
        for (int c = 0; c < 4; ++c) {
          part[nt][c] += __shfl_xor(part[nt][c], 16, 64);
          part[nt][c] += __shfl_xor(part[nt][c], 32, 64);
        }
      if (lk == 0) {
        #pragma unroll
        for (int nt = 0; nt < 8; ++nt)
          *(f32x4*)&s_partT[w][nt * 16 + lr][kh * 4] = part[nt];
      }
    }
    __syncthreads();
    if (t < 256) {
      const int h = t >> 1, q = t & 1;
      f32x4 sum = (f32x4){0.f, 0.f, 0.f, 0.f};
      #pragma unroll
      for (int ww = 0; ww < 8; ++ww)
        sum += *(const f32x4*)&s_partT[ww][h][q * 4];
      *(f32x4*)&s_highT[h][q * 4] = sum;
    }
    __syncthreads();

    // (c) r[s][k] += inv[s]*dot(high[k], low[s]) from registers; 2 k-passes
    if (it < 2) {
      #pragma unroll
      for (int kh = 0; kh < 2; ++kh) {
        f32x4 hi[8];
        #pragma unroll
        for (int nt = 0; nt < 8; ++nt)
          hi[nt] = *(const f32x4*)&s_highT[nt * 16 + lr][kh * 4];
        #pragma unroll
        for (int mt = 0; mt < 2; ++mt)
          #pragma unroll
          for (int j = 0; j < 4; ++j) {
            const int row = w * 32 + mt * 16 + lk * 4 + j;
            f32x4 d = (f32x4){0.f, 0.f, 0.f, 0.f};
            #pragma unroll
            for (int nt = 0; nt < 8; ++nt) {
              const float a = acc[mt][nt][j];
              d.x = fmaf(a, hi[nt].x, d.x);
              d.y = fmaf(a, hi[nt].y, d.y);
              d.z = fmaf(a, hi[nt].z, d.z);
              d.w = fmaf(a, hi[nt].w, d.w);
            }
            #pragma unroll
            for (int c = 0; c < 4; ++c) {
              d[c] += __shfl_xor(d[c], 1, 64);
              d[c] += __shfl_xor(d[c], 2, 64);
              d[c] += __shfl_xor(d[c], 4, 64);
              d[c] += __shfl_xor(d[c], 8, 64);
            }
            if (lr == 0 && row < sl) {
              const float inv = s_inv[row];
              float4 pv = *(const float4*)&s_p[row][kh * 4];
              pv.x = fmaf(d.x, inv, pv.x);
              pv.y = fmaf(d.y, inv, pv.y);
              pv.z = fmaf(d.z, inv, pv.z);
              pv.w = fmaf(d.w, inv, pv.w);
              *(float4*)&s_p[row][kh * 4] = pv;
            }
          }
      }
    }
    __syncthreads();
  }

  // ---------------- squash + output ----------------
  if (t < 64) {
    const int k = t >> 3, part = t & 7;
    float n2 = 0.f;
    #pragma unroll
    for (int q = 0; q < 16; ++q) {
      const float v = s_highT[part * 16 + q][k];
      n2 = fmaf(v, v, n2);
    }
    n2 += __shfl_xor(n2, 1, 64);
    n2 += __shfl_xor(n2, 2, 64);
    n2 += __shfl_xor(n2, 4, 64);
    if (part == 0) {
      const float n = sqrtf(n2), ne = fmaxf(n, 1e-7f), sq = ne * ne;
      float sc = sq / ((1.0f + sq) * ne);
      if (k >= ka) sc = 0.f;
      s_scale[k] = sc;
    }
  }
  __syncthreads();
  {
    float* ob = out + (size_t)b * (KMAX * HH);
    #pragma unroll
    for (int m = 0; m < 2; ++m) {
      const int idx = m * 512 + t;
      const int k = idx >> 7, h = idx & 127;
      ob[k * HH + h]    = s_highT[h][k] * s_scale[k];
      ob[KE * HH + idx] = 0.f;
    }
    if (t < KMAX)
      out[(size_t)NB * KMAX * HH + (size_t)b * KMAX + t] = (t < ka) ? 1.f : 0.f;
  }
}

// ===================== Fallback: round-3 fused kernel =======================
#define LOWPAD 132
__global__ __launch_bounds__(512) void capsule_fused(
    const float* __restrict__ inputs, const int* __restrict__ seq_len,
    const float* __restrict__ Wm, const float* __restrict__ r_init,
    float* __restrict__ out) {
  __shared__ __align__(16) float s_low[SS][LOWPAD];
  __shared__ __align__(16) float s_p[SS][KE];
  __shared__ __align__(16) float s_part[2][KE][HH];
  __shared__ __align__(16) float s_high[KE][HH];
  __shared__ __align__(16) float s_inv[SS];
  __shared__ __align__(16) float s_scale[KE];
  const int b = blockIdx.x, t = threadIdx.x, sl = seq_len[b];
  const int ilog = 31 - __clz(sl);
  float nh = ((sl & (sl - 1)) == 0) ? (float)ilog : log2f((float)sl);
  nh = fmaxf(1.0f, fminf(16.0f, nh));
  const int ka = (int)ceilf(nh);
  {
    const int hg = t & 15, h0 = hg * 8, rg = t >> 4;
    const float* inb = inputs + (size_t)b * SS * LL;
    for (int sweep = 0; sweep < 8; ++sweep) {
      const int s = sweep * 32 + rg;
      float a0=0.f,a1=0.f,a2=0.f,a3=0.f,a4=0.f,a5=0.f,a6=0.f,a7=0.f;
      if (s < sl) {
        const float* inp = inb + (size_t)s * LL;
        for (int ll = 0; ll < LL; ll += 4) {
          const float4 iv = *(const float4*)(inp + ll);
          #pragma unroll
          for (int d = 0; d < 4; ++d) {
            const float f = (d==0)?iv.x:(d==1)?iv.y:(d==2)?iv.z:iv.w;
            const float* wp = Wm + (size_t)(ll + d) * HH + h0;
            const float4 wa = *(const float4*)(wp);
            const float4 wb = *(const float4*)(wp + 4);
            a0=fmaf(f,wa.x,a0); a1=fmaf(f,wa.y,a1); a2=fmaf(f,wa.z,a2); a3=fmaf(f,wa.w,a3);
            a4=fmaf(f,wb.x,a4); a5=fmaf(f,wb.y,a5); a6=fmaf(f,wb.z,a6); a7=fmaf(f,wb.w,a7);
          }
        }
      }
      s_low[s][h0+0]=a0; s_low[s][h0+1]=a1; s_low[s][h0+2]=a2; s_low[s][h0+3]=a3;
      s_low[s][h0+4]=a4; s_low[s][h0+5]=a5; s_low[s][h0+6]=a6; s_low[s][h0+7]=a7;
    }
  }
  for (int idx = t; idx < SS * KE; idx += 512) {
    const int s = idx >> 3, k = idx & 7;
    s_p[s][k] = r_init[((size_t)b * SS + s) * KMAX + k];
  }
  __syncthreads();
  if (t < SS) {
    float n2 = 0.f;
    for (int h = 0; h < HH; ++h) { const float v = s_low[t][h]; n2 = fmaf(v, v, n2); }
    s_inv[t] = 1.0f / fmaxf(sqrtf(n2), 1e-12f);
  }
  __syncthreads();
  for (int it = 0; it < 3; ++it) {
    if (t < SS) {
      const int s = t;
      float rk0=s_p[s][0],rk1=s_p[s][1],rk2=s_p[s][2],rk3=s_p[s][3];
      float rk4=s_p[s][4],rk5=s_p[s][5],rk6=s_p[s][6],rk7=s_p[s][7];
      float m = rk0;
      if (1<ka) m=fmaxf(m,rk1); if (2<ka) m=fmaxf(m,rk2); if (3<ka) m=fmaxf(m,rk3);
      if (4<ka) m=fmaxf(m,rk4); if (5<ka) m=fmaxf(m,rk5); if (6<ka) m=fmaxf(m,rk6);
      if (7<ka) m=fmaxf(m,rk7);
      const float e0=expf(rk0-m);
      const float e1=(1<ka)?expf(rk1-m):0.f, e2=(2<ka)?expf(rk2-m):0.f;
      const float e3=(3<ka)?expf(rk3-m):0.f, e4=(4<ka)?expf(rk4-m):0.f;
      const float e5=(5<ka)?expf(rk5-m):0.f, e6=(6<ka)?expf(rk6-m):0.f;
      const float e7=(7<ka)?expf(rk7-m):0.f;
      const float sum=((e0+e1)+(e2+e3))+((e4+e5)+(e6+e7));
      const float rs=(s<sl)?(1.0f/sum):0.f;
      s_p[s][0]=e0*rs; s_p[s][1]=e1*rs; s_p[s][2]=e2*rs; s_p[s][3]=e3*rs;
      s_p[s][4]=e4*rs; s_p[s][5]=e5*rs; s_p[s][6]=e6*rs; s_p[s][7]=e7*rs;
    }
    __syncthreads();
    {
      const int g=t>>8, w4=(t>>6)&3, k=(t&63)>>3, hg=t&7, h0=w4*32+hg*4;
      float a0=0.f,a1=0.f,a2=0.f,a3=0.f;
      const int sbase=g*128;
      for (int i=0;i<128;++i) {
        const int s=sbase+i;
        const float4 v=*(const float4*)&s_low[s][h0];
        const float p=s_p[s][k];
        a0=fmaf(v.x,p,a0); a1=fmaf(v.y,p,a1); a2=fmaf(v.z,p,a2); a3=fmaf(v.w,p,a3);
      }
      s_part[g][k][h0+0]=a0; s_part[g][k][h0+1]=a1;
      s_part[g][k][h0+2]=a2; s_part[g][k][h0+3]=a3;
    }
    __syncthreads();
    for (int idx=t; idx<KE*HH; idx+=512) {
      const int k=idx>>7, h=idx&127;
      s_high[k][h]=s_part[0][k][h]+s_part[1][k][h];
    }
    __syncthreads();
    if (it < 2) {
      const int s=t&255, k0=(t>>8)<<2;
      float d0=0.f,d1=0.f,d2=0.f,d3=0.f;
      for (int h=0;h<HH;h+=4) {
        const float4 v=*(const float4*)&s_low[s][h];
        const float4 q0=*(const float4*)&s_high[k0+0][h];
        const float4 q1=*(const float4*)&s_high[k0+1][h];
        const float4 q2=*(const float4*)&s_high[k0+2][h];
        const float4 q3=*(const float4*)&s_high[k0+3][h];
        d0=fmaf(v.x,q0.x,fmaf(v.y,q0.y,fmaf(v.z,q0.z,fmaf(v.w,q0.w,d0))));
        d1=fmaf(v.x,q1.x,fmaf(v.y,q1.y,fmaf(v.z,q1.z,fmaf(v.w,q1.w,d1))));
        d2=fmaf(v.x,q2.x,fmaf(v.y,q2.y,fmaf(v.z,q2.z,fmaf(v.w,q2.w,d2))));
        d3=fmaf(v.x,q3.x,fmaf(v.y,q3.y,fmaf(v.z,q3.z,fmaf(v.w,q3.w,d3))));
      }
      const float inv=s_inv[s];
      s_p[s][k0+0]=fmaf(d0,inv,s_p[s][k0+0]);
      s_p[s][k0+1]=fmaf(d1,inv,s_p[s][k0+1]);
      s_p[s][k0+2]=fmaf(d2,inv,s_p[s][k0+2]);
      s_p[s][k0+3]=fmaf(d3,inv,s_p[s][k0+3]);
    }
    __syncthreads();
  }
  if (t < KE) {
    float n2=0.f;
    for (int h=0;h<HH;++h){ const float v=s_high[t][h]; n2=fmaf(v,v,n2); }
    const float n=sqrtf(n2), ne=fmaxf(n,1e-7f), sq=ne*ne;
    float sc=sq/((1.0f+sq)*ne);
    if (t>=ka) sc=0.f;
    s_scale[t]=sc;
  }
  __syncthreads();
  {
    const int w2=t>>6, lane=t&63;
    const float sc=s_scale[w2];
    float* ob=out+(size_t)b*(KMAX*HH);
    ob[w2*HH+lane]=s_high[w2][lane]*sc;
    ob[w2*HH+lane+64]=s_high[w2][lane+64]*sc;
    ob[KE*HH+t]=0.0f; ob[KE*HH+512+t]=0.0f;
    if (t<KMAX) {
      float* om=out+(size_t)NB*KMAX*HH;
      om[b*KMAX+t]=(t<ka)?1.0f:0.0f;
    }
  }
}

extern "C" void kernel_launch(void* const* d_in, const int* in_sizes, int n_in,
                              void* d_out, int out_size, void* d_ws, size_t ws_size,
                              hipStream_t stream) {
  const float* inputs  = (const float*)d_in[0];
  const int*   seq_len = (const int*)d_in[1];
  const float* Wm      = (const float*)d_in[2];
  const float* r_init  = (const float*)d_in[3];
  float* out           = (float*)d_out;
  const size_t wt_bytes = (size_t)HH * LL * sizeof(u16);   // 64 KB each
  if (ws_size >= 2 * wt_bytes) {
    u16* wt_hi = (u16*)d_ws;
    u16* wt_lo = wt_hi + (size_t)HH * LL;
    hipLaunchKernelGGL(prep_w, dim3(128), dim3(256), 0, stream, Wm, wt_hi, wt_lo);
    hipLaunchKernelGGL(capsule_reg, dim3(NB), dim3(512), 0, stream,
                       inputs, seq_len, wt_hi, wt_lo, r_init, out);
  } else {
    hipLaunchKernelGGL(capsule_fused, dim3(NB), dim3(512), 0, stream,
                       inputs, seq_len, Wm, r_init, out);
  }
}

// Round 14
// 134.633 us; speedup vs baseline: 1.4473x; 1.4473x over previous
//
#include <hip/hip_runtime.h>
#include <hip/hip_bf16.h>

#define NB 1024
#define SS 256
#define LL 256
#define HH 128
#define KMAX 16
#define KE 8
#define LP 132

typedef __attribute__((ext_vector_type(8))) short bf16x8;
typedef __attribute__((ext_vector_type(4))) float f32x4;
typedef unsigned short u16;
typedef unsigned int u32;

__device__ __forceinline__ void split_bf16(float a, u16& hi, u16& lo) {
  u32 u = __float_as_uint(a);
  u32 hb = (u + 0x8000u) & 0xFFFF0000u;      // RTN-ish bf16 hi
  float lf = a - __uint_as_float(hb);        // exact residual
  hi = (u16)(hb >> 16);
  lo = (u16)(__float_as_uint(lf) >> 16);
}

// ---- prep: W[l][h] -> Wt_hi[h][l], Wt_lo[h][l] (bf16 split, transposed) ----
__global__ __launch_bounds__(256) void prep_w(
    const float* __restrict__ Wm, u16* __restrict__ wt_hi, u16* __restrict__ wt_lo) {
  const int id = blockIdx.x * 256 + threadIdx.x;
  const int h = id & 127, ll = id >> 7;
  const float a = Wm[(size_t)ll * HH + h];
  u16 hi, lo;
  split_bf16(a, hi, lo);
  wt_hi[h * LL + ll] = hi;
  wt_lo[h * LL + ll] = lo;
}

// =================== Fused kernel: GEMM(MFMA) + routing =====================
// R9 configuration (best measured: 134.7 us). 1 block = 1 batch, 512 threads.
// s_low[256][132] fp32; first 61440 B double as GEMM staging (barrier-fenced).
__global__ __launch_bounds__(512) void capsule_one(
    const float* __restrict__ inputs, const int* __restrict__ seq_len,
    const u16* __restrict__ wt_hi, const u16* __restrict__ wt_lo,
    const float* __restrict__ r_init, float* __restrict__ out) {
  __shared__ __align__(16) float s_low[SS][LP];      // 135168
  __shared__ __align__(16) float s_p[SS][KE];        //   8192
  __shared__ __align__(16) float s_part[2][KE][HH];  //   8192
  __shared__ __align__(16) float s_high[KE][HH];     //   4096
  __shared__ __align__(16) float s_inv[SS];          //   1024
  __shared__ __align__(16) float s_scale[KE];        //     32  => 156704 B

  const int b = blockIdx.x, t = threadIdx.x, sl = seq_len[b];
  const int w = t >> 6, l = t & 63, half = l >> 5, l31 = l & 31;

  const int ilog = 31 - __clz(sl);
  float nhf = ((sl & (sl - 1)) == 0) ? (float)ilog : log2f((float)sl);
  nhf = fmaxf(1.0f, fminf(16.0f, nhf));
  const int ka = (int)ceilf(nhf);

  // ---- s_p init (independent of GEMM; overlaps with A prefetch) ----
  #pragma unroll
  for (int m = 0; m < 4; ++m) {
    const int idx = m * 512 + t;
    s_p[idx >> 3][idx & 7] = r_init[((size_t)b * SS + (idx >> 3)) * KMAX + (idx & 7)];
  }

  // ---- GEMM phase: staging aliased over s_low[0..61440B) ----
  u16* Ahi = (u16*)&s_low[0][0];        // [256][40] u16 = 20480 B
  u16* Alo = Ahi + 256 * 40;            // 20480 B
  u16* Bhs = Alo + 256 * 40;            // [128][40] u16 = 10240 B
  u16* Bls = Bhs + 128 * 40;            // 10240 B  (total 61440 B)

  const int lr = l & 15, lk = l >> 4;
  f32x4 acc[2][8];
  #pragma unroll
  for (int mt = 0; mt < 2; ++mt)
    #pragma unroll
    for (int nt = 0; nt < 8; ++nt) acc[mt][nt] = (f32x4){0.f, 0.f, 0.f, 0.f};

  const float* Ab = inputs + (size_t)b * SS * LL;
  const int arow = t >> 3, aq = t & 7;           // A-stage: rows arow+{0,64,128,192}
  const int bcol = t >> 2, bpart = t & 3;        // B-stage: 16B per thread per buf
  const bool wave_active = (w * 32) < sl;

  float4 pre0, pre1, pre2, pre3;
  uint4 pbh, pbl;
  {
    if (arow < sl)        pre0 = *(const float4*)(Ab + (size_t)arow * LL + aq * 4);
    if (arow + 64 < sl)   pre1 = *(const float4*)(Ab + (size_t)(arow + 64) * LL + aq * 4);
    if (arow + 128 < sl)  pre2 = *(const float4*)(Ab + (size_t)(arow + 128) * LL + aq * 4);
    if (arow + 192 < sl)  pre3 = *(const float4*)(Ab + (size_t)(arow + 192) * LL + aq * 4);
    pbh = *(const uint4*)(wt_hi + (size_t)bcol * LL + bpart * 8);
    pbl = *(const uint4*)(wt_lo + (size_t)bcol * LL + bpart * 8);
  }

  for (int kc = 0; kc < LL; kc += 32) {
    // consume prefetched A: split -> LDS
    #pragma unroll
    for (int m = 0; m < 4; ++m) {
      const int row = arow + m * 64;
      const float4 v = (m == 0) ? pre0 : (m == 1) ? pre1 : (m == 2) ? pre2 : pre3;
      if (row < sl) {
        u16 h0,h1,h2,h3, l0,l1,l2,l3;
        split_bf16(v.x, h0, l0); split_bf16(v.y, h1, l1);
        split_bf16(v.z, h2, l2); split_bf16(v.w, h3, l3);
        uint2 hp, lp;
        hp.x = (u32)h0 | ((u32)h1 << 16);  hp.y = (u32)h2 | ((u32)h3 << 16);
        lp.x = (u32)l0 | ((u32)l1 << 16);  lp.y = (u32)l2 | ((u32)l3 << 16);
        *(uint2*)&Ahi[row * 40 + aq * 4] = hp;
        *(uint2*)&Alo[row * 40 + aq * 4] = lp;
      }
    }
    // consume prefetched B
    *(uint4*)&Bhs[bcol * 40 + bpart * 8] = pbh;
    *(uint4*)&Bls[bcol * 40 + bpart * 8] = pbl;
    // issue next-chunk loads (hide HBM/L2 latency under barrier + MFMA)
    if (kc + 32 < LL) {
      const int kn = kc + 32;
      if (arow < sl)        pre0 = *(const float4*)(Ab + (size_t)arow * LL + kn + aq * 4);
      if (arow + 64 < sl)   pre1 = *(const float4*)(Ab + (size_t)(arow + 64) * LL + kn + aq * 4);
      if (arow + 128 < sl)  pre2 = *(const float4*)(Ab + (size_t)(arow + 128) * LL + kn + aq * 4);
      if (arow + 192 < sl)  pre3 = *(const float4*)(Ab + (size_t)(arow + 192) * LL + kn + aq * 4);
      pbh = *(const uint4*)(wt_hi + (size_t)bcol * LL + kn + bpart * 8);
      pbl = *(const uint4*)(wt_lo + (size_t)bcol * LL + kn + bpart * 8);
    }
    __syncthreads();

    if (wave_active) {
      bf16x8 ah[2], al[2];
      #pragma unroll
      for (int mt = 0; mt < 2; ++mt) {
        const int row = w * 32 + mt * 16 + lr;
        ah[mt] = *(const bf16x8*)&Ahi[row * 40 + lk * 8];
        al[mt] = *(const bf16x8*)&Alo[row * 40 + lk * 8];
      }
      #pragma unroll
      for (int nt = 0; nt < 8; ++nt) {
        const int col = nt * 16 + lr;
        const bf16x8 bhf = *(const bf16x8*)&Bhs[col * 40 + lk * 8];
        const bf16x8 blf = *(const bf16x8*)&Bls[col * 40 + lk * 8];
        #pragma unroll
        for (int mt = 0; mt < 2; ++mt) {
          acc[mt][nt] = __builtin_amdgcn_mfma_f32_16x16x32_bf16(ah[mt], bhf, acc[mt][nt], 0, 0, 0);
          acc[mt][nt] = __builtin_amdgcn_mfma_f32_16x16x32_bf16(ah[mt], blf, acc[mt][nt], 0, 0, 0);
          acc[mt][nt] = __builtin_amdgcn_mfma_f32_16x16x32_bf16(al[mt], bhf, acc[mt][nt], 0, 0, 0);
        }
      }
    }
    __syncthreads();   // also fences staging before epilogue overwrites it
  }

  // ---- epilogue: acc -> s_low fp32 (rows >= sl forced to exact 0) ----
  #pragma unroll
  for (int mt = 0; mt < 2; ++mt)
    #pragma unroll
    for (int j = 0; j < 4; ++j) {
      const int row = w * 32 + mt * 16 + lk * 4 + j;
      const bool live = row < sl;
      #pragma unroll
      for (int nt = 0; nt < 8; ++nt)
        s_low[row][nt * 16 + lr] = live ? acc[mt][nt][j] : 0.f;
    }
  __syncthreads();

  // ---- row inverse norms ----
  {
    const int s = w * 32 + l31;
    float n2 = 0.f;
    #pragma unroll
    for (int q = 0; q < 16; ++q) {
      const float4 v = *(const float4*)&s_low[s][half * 64 + q * 4];
      n2 = fmaf(v.x, v.x, fmaf(v.y, v.y, fmaf(v.z, v.z, fmaf(v.w, v.w, n2))));
    }
    n2 += __shfl_xor(n2, 32, 64);
    if (half == 0) s_inv[s] = 1.0f / fmaxf(sqrtf(n2), 1e-12f);
  }
  __syncthreads();

  for (int it = 0; it < 3; ++it) {
    // (a) masked softmax
    if (t < SS) {
      const int s = t;
      const float4 ra = *(const float4*)&s_p[s][0];
      const float4 rb = *(const float4*)&s_p[s][4];
      float m = ra.x;
      if (1 < ka) m = fmaxf(m, ra.y);
      if (2 < ka) m = fmaxf(m, ra.z);
      if (3 < ka) m = fmaxf(m, ra.w);
      if (4 < ka) m = fmaxf(m, rb.x);
      if (5 < ka) m = fmaxf(m, rb.y);
      if (6 < ka) m = fmaxf(m, rb.z);
      if (7 < ka) m = fmaxf(m, rb.w);
      const float e0 = expf(ra.x - m);
      const float e1 = (1 < ka) ? expf(ra.y - m) : 0.f;
      const float e2 = (2 < ka) ? expf(ra.z - m) : 0.f;
      const float e3 = (3 < ka) ? expf(ra.w - m) : 0.f;
      const float e4 = (4 < ka) ? expf(rb.x - m) : 0.f;
      const float e5 = (5 < ka) ? expf(rb.y - m) : 0.f;
      const float e6 = (6 < ka) ? expf(rb.z - m) : 0.f;
      const float e7 = (7 < ka) ? expf(rb.w - m) : 0.f;
      const float sum = ((e0 + e1) + (e2 + e3)) + ((e4 + e5) + (e6 + e7));
      const float rs = (s < sl) ? (1.0f / sum) : 0.f;
      *(float4*)&s_p[s][0] = make_float4(e0 * rs, e1 * rs, e2 * rs, e3 * rs);
      *(float4*)&s_p[s][4] = make_float4(e4 * rs, e5 * rs, e6 * rs, e7 * rs);
    }
    __syncthreads();

    // (b) high partials: 8 waves = (g: s-half, kq: k-pair); sl-trimmed
    {
      const int g = w >> 2, kq = w & 3, k0 = kq * 2;
      const int slg = min(128, max(0, sl - g * 128));
      const int ni = (slg + 1) >> 1;
      float a0x = 0.f, a0y = 0.f, a0z = 0.f, a0w = 0.f;
      float a1x = 0.f, a1y = 0.f, a1z = 0.f, a1w = 0.f;
      for (int i = 0; i < ni; ++i) {
        const int s = g * 128 + i * 2 + half;
        const float4 v = *(const float4*)&s_low[s][l31 * 4];
        const float2 p2 = *(const float2*)&s_p[s][k0];
        a0x = fmaf(v.x, p2.x, a0x); a0y = fmaf(v.y, p2.x, a0y);
        a0z = fmaf(v.z, p2.x, a0z); a0w = fmaf(v.w, p2.x, a0w);
        a1x = fmaf(v.x, p2.y, a1x); a1y = fmaf(v.y, p2.y, a1y);
        a1z = fmaf(v.z, p2.y, a1z); a1w = fmaf(v.w, p2.y, a1w);
      }
      a0x += __shfl_xor(a0x, 32, 64); a0y += __shfl_xor(a0y, 32, 64);
      a0z += __shfl_xor(a0z, 32, 64); a0w += __shfl_xor(a0w, 32, 64);
      a1x += __shfl_xor(a1x, 32, 64); a1y += __shfl_xor(a1y, 32, 64);
      a1z += __shfl_xor(a1z, 32, 64); a1w += __shfl_xor(a1w, 32, 64);
      if (half == 0) {
        *(float4*)&s_part[g][k0][l31 * 4]     = make_float4(a0x, a0y, a0z, a0w);
        *(float4*)&s_part[g][k0 + 1][l31 * 4] = make_float4(a1x, a1y, a1z, a1w);
      }
    }
    __syncthreads();
    #pragma unroll
    for (int m = 0; m < 2; ++m) {
      const int idx = m * 512 + t;
      const int k = idx >> 7, h = idx & 127;
      s_high[k][h] = s_part[0][k][h] + s_part[1][k][h];
    }
    __syncthreads();

    // (c) r[s][k] += inv[s]*dot(high[k],low[s]); skip rows >= sl
    if (it < 2) {
      const int s = w * 32 + l31;
      if (s < sl) {
        float d0 = 0.f, d1 = 0.f, d2 = 0.f, d3 = 0.f;
        float d4 = 0.f, d5 = 0.f, d6 = 0.f, d7 = 0.f;
        #pragma unroll
        for (int q = 0; q < 16; ++q) {
          const int h = half * 64 + q * 4;
          const float4 v = *(const float4*)&s_low[s][h];
          const float4 h0 = *(const float4*)&s_high[0][h];
          const float4 h1 = *(const float4*)&s_high[1][h];
          const float4 h2 = *(const float4*)&s_high[2][h];
          const float4 h3 = *(const float4*)&s_high[3][h];
          const float4 h4 = *(const float4*)&s_high[4][h];
          const float4 h5 = *(const float4*)&s_high[5][h];
          const float4 h6 = *(const float4*)&s_high[6][h];
          const float4 h7 = *(const float4*)&s_high[7][h];
          d0 = fmaf(v.x, h0.x, fmaf(v.y, h0.y, fmaf(v.z, h0.z, fmaf(v.w, h0.w, d0))));
          d1 = fmaf(v.x, h1.x, fmaf(v.y, h1.y, fmaf(v.z, h1.z, fmaf(v.w, h1.w, d1))));
          d2 = fmaf(v.x, h2.x, fmaf(v.y, h2.y, fmaf(v.z, h2.z, fmaf(v.w, h2.w, d2))));
          d3 = fmaf(v.x, h3.x, fmaf(v.y, h3.y, fmaf(v.z, h3.z, fmaf(v.w, h3.w, d3))));
          d4 = fmaf(v.x, h4.x, fmaf(v.y, h4.y, fmaf(v.z, h4.z, fmaf(v.w, h4.w, d4))));
          d5 = fmaf(v.x, h5.x, fmaf(v.y, h5.y, fmaf(v.z, h5.z, fmaf(v.w, h5.w, d5))));
          d6 = fmaf(v.x, h6.x, fmaf(v.y, h6.y, fmaf(v.z, h6.z, fmaf(v.w, h6.w, d6))));
          d7 = fmaf(v.x, h7.x, fmaf(v.y, h7.y, fmaf(v.z, h7.z, fmaf(v.w, h7.w, d7))));
        }
        d0 += __shfl_xor(d0, 32, 64); d1 += __shfl_xor(d1, 32, 64);
        d2 += __shfl_xor(d2, 32, 64); d3 += __shfl_xor(d3, 32, 64);
        d4 += __shfl_xor(d4, 32, 64); d5 += __shfl_xor(d5, 32, 64);
        d6 += __shfl_xor(d6, 32, 64); d7 += __shfl_xor(d7, 32, 64);
        if (half == 0) {
          const float inv = s_inv[s];
          float4 p0 = *(const float4*)&s_p[s][0];
          float4 p1 = *(const float4*)&s_p[s][4];
          p0.x = fmaf(d0, inv, p0.x); p0.y = fmaf(d1, inv, p0.y);
          p0.z = fmaf(d2, inv, p0.z); p0.w = fmaf(d3, inv, p0.w);
          p1.x = fmaf(d4, inv, p1.x); p1.y = fmaf(d5, inv, p1.y);
          p1.z = fmaf(d6, inv, p1.z); p1.w = fmaf(d7, inv, p1.w);
          *(float4*)&s_p[s][0] = p0;
          *(float4*)&s_p[s][4] = p1;
        }
      }
    }
    __syncthreads();
  }

  // ---- squash + output ----
  if (t < 64) {
    const int k = t >> 3, part = t & 7;
    float n2 = 0.f;
    #pragma unroll
    for (int q = 0; q < 4; ++q) {
      const float4 v = *(const float4*)&s_high[k][part * 16 + q * 4];
      n2 = fmaf(v.x, v.x, fmaf(v.y, v.y, fmaf(v.z, v.z, fmaf(v.w, v.w, n2))));
    }
    n2 += __shfl_xor(n2, 1, 64);
    n2 += __shfl_xor(n2, 2, 64);
    n2 += __shfl_xor(n2, 4, 64);
    if (part == 0) {
      const float n = sqrtf(n2), ne = fmaxf(n, 1e-7f), sq = ne * ne;
      float sc = sq / ((1.0f + sq) * ne);
      if (k >= ka) sc = 0.f;
      s_scale[k] = sc;
    }
  }
  __syncthreads();
  {
    float* ob = out + (size_t)b * (KMAX * HH);
    #pragma unroll
    for (int m = 0; m < 2; ++m) {
      const int idx = m * 512 + t;
      const int k = idx >> 7, h = idx & 127;
      ob[k * HH + h]    = s_high[k][h] * s_scale[k];
      ob[KE * HH + idx] = 0.f;
    }
    if (t < KMAX)
      out[(size_t)NB * KMAX * HH + (size_t)b * KMAX + t] = (t < ka) ? 1.f : 0.f;
  }
}

// ===================== Fallback: round-3 fused kernel =======================
#define LOWPAD 132
__global__ __launch_bounds__(512) void capsule_fused(
    const float* __restrict__ inputs, const int* __restrict__ seq_len,
    const float* __restrict__ Wm, const float* __restrict__ r_init,
    float* __restrict__ out) {
  __shared__ __align__(16) float s_low[SS][LOWPAD];
  __shared__ __align__(16) float s_p[SS][KE];
  __shared__ __align__(16) float s_part[2][KE][HH];
  __shared__ __align__(16) float s_high[KE][HH];
  __shared__ __align__(16) float s_inv[SS];
  __shared__ __align__(16) float s_scale[KE];
  const int b = blockIdx.x, t = threadIdx.x, sl = seq_len[b];
  const int ilog = 31 - __clz(sl);
  float nh = ((sl & (sl - 1)) == 0) ? (float)ilog : log2f((float)sl);
  nh = fmaxf(1.0f, fminf(16.0f, nh));
  const int ka = (int)ceilf(nh);
  {
    const int hg = t & 15, h0 = hg * 8, rg = t >> 4;
    const float* inb = inputs + (size_t)b * SS * LL;
    for (int sweep = 0; sweep < 8; ++sweep) {
      const int s = sweep * 32 + rg;
      float a0=0.f,a1=0.f,a2=0.f,a3=0.f,a4=0.f,a5=0.f,a6=0.f,a7=0.f;
      if (s < sl) {
        const float* inp = inb + (size_t)s * LL;
        for (int ll = 0; ll < LL; ll += 4) {
          const float4 iv = *(const float4*)(inp + ll);
          #pragma unroll
          for (int d = 0; d < 4; ++d) {
            const float f = (d==0)?iv.x:(d==1)?iv.y:(d==2)?iv.z:iv.w;
            const float* wp = Wm + (size_t)(ll + d) * HH + h0;
            const float4 wa = *(const float4*)(wp);
            const float4 wb = *(const float4*)(wp + 4);
            a0=fmaf(f,wa.x,a0); a1=fmaf(f,wa.y,a1); a2=fmaf(f,wa.z,a2); a3=fmaf(f,wa.w,a3);
            a4=fmaf(f,wb.x,a4); a5=fmaf(f,wb.y,a5); a6=fmaf(f,wb.z,a6); a7=fmaf(f,wb.w,a7);
          }
        }
      }
      s_low[s][h0+0]=a0; s_low[s][h0+1]=a1; s_low[s][h0+2]=a2; s_low[s][h0+3]=a3;
      s_low[s][h0+4]=a4; s_low[s][h0+5]=a5; s_low[s][h0+6]=a6; s_low[s][h0+7]=a7;
    }
  }
  for (int idx = t; idx < SS * KE; idx += 512) {
    const int s = idx >> 3, k = idx & 7;
    s_p[s][k] = r_init[((size_t)b * SS + s) * KMAX + k];
  }
  __syncthreads();
  if (t < SS) {
    float n2 = 0.f;
    for (int h = 0; h < HH; ++h) { const float v = s_low[t][h]; n2 = fmaf(v, v, n2); }
    s_inv[t] = 1.0f / fmaxf(sqrtf(n2), 1e-12f);
  }
  __syncthreads();
  for (int it = 0; it < 3; ++it) {
    if (t < SS) {
      const int s = t;
      float rk0=s_p[s][0],rk1=s_p[s][1],rk2=s_p[s][2],rk3=s_p[s][3];
      float rk4=s_p[s][4],rk5=s_p[s][5],rk6=s_p[s][6],rk7=s_p[s][7];
      float m = rk0;
      if (1<ka) m=fmaxf(m,rk1); if (2<ka) m=fmaxf(m,rk2); if (3<ka) m=fmaxf(m,rk3);
      if (4<ka) m=fmaxf(m,rk4); if (5<ka) m=fmaxf(m,rk5); if (6<ka) m=fmaxf(m,rk6);
      if (7<ka) m=fmaxf(m,rk7);
      const float e0=expf(rk0-m);
      const float e1=(1<ka)?expf(rk1-m):0.f, e2=(2<ka)?expf(rk2-m):0.f;
      const float e3=(3<ka)?expf(rk3-m):0.f, e4=(4<ka)?expf(rk4-m):0.f;
      const float e5=(5<ka)?expf(rk5-m):0.f, e6=(6<ka)?expf(rk6-m):0.f;
      const float e7=(7<ka)?expf(rk7-m):0.f;
      const float sum=((e0+e1)+(e2+e3))+((e4+e5)+(e6+e7));
      const float rs=(s<sl)?(1.0f/sum):0.f;
      s_p[s][0]=e0*rs; s_p[s][1]=e1*rs; s_p[s][2]=e2*rs; s_p[s][3]=e3*rs;
      s_p[s][4]=e4*rs; s_p[s][5]=e5*rs; s_p[s][6]=e6*rs; s_p[s][7]=e7*rs;
    }
    __syncthreads();
    {
      const int g=t>>8, w4=(t>>6)&3, k=(t&63)>>3, hg=t&7, h0=w4*32+hg*4;
      float a0=0.f,a1=0.f,a2=0.f,a3=0.f;
      const int sbase=g*128;
      for (int i=0;i<128;++i) {
        const int s=sbase+i;
        const float4 v=*(const float4*)&s_low[s][h0];
        const float p=s_p[s][k];
        a0=fmaf(v.x,p,a0); a1=fmaf(v.y,p,a1); a2=fmaf(v.z,p,a2); a3=fmaf(v.w,p,a3);
      }
      s_part[g][k][h0+0]=a0; s_part[g][k][h0+1]=a1;
      s_part[g][k][h0+2]=a2; s_part[g][k][h0+3]=a3;
    }
    __syncthreads();
    for (int idx=t; idx<KE*HH; idx+=512) {
      const int k=idx>>7, h=idx&127;
      s_high[k][h]=s_part[0][k][h]+s_part[1][k][h];
    }
    __syncthreads();
    if (it < 2) {
      const int s=t&255, k0=(t>>8)<<2;
      float d0=0.f,d1=0.f,d2=0.f,d3=0.f;
      for (int h=0;h<HH;h+=4) {
        const float4 v=*(const float4*)&s_low[s][h];
        const float4 q0=*(const float4*)&s_high[k0+0][h];
        const float4 q1=*(const float4*)&s_high[k0+1][h];
        const float4 q2=*(const float4*)&s_high[k0+2][h];
        const float4 q3=*(const float4*)&s_high[k0+3][h];
        d0=fmaf(v.x,q0.x,fmaf(v.y,q0.y,fmaf(v.z,q0.z,fmaf(v.w,q0.w,d0))));
        d1=fmaf(v.x,q1.x,fmaf(v.y,q1.y,fmaf(v.z,q1.z,fmaf(v.w,q1.w,d1))));
        d2=fmaf(v.x,q2.x,fmaf(v.y,q2.y,fmaf(v.z,q2.z,fmaf(v.w,q2.w,d2))));
        d3=fmaf(v.x,q3.x,fmaf(v.y,q3.y,fmaf(v.z,q3.z,fmaf(v.w,q3.w,d3))));
      }
      const float inv=s_inv[s];
      s_p[s][k0+0]=fmaf(d0,inv,s_p[s][k0+0]);
      s_p[s][k0+1]=fmaf(d1,inv,s_p[s][k0+1]);
      s_p[s][k0+2]=fmaf(d2,inv,s_p[s][k0+2]);
      s_p[s][k0+3]=fmaf(d3,inv,s_p[s][k0+3]);
    }
    __syncthreads();
  }
  if (t < KE) {
    float n2=0.f;
    for (int h=0;h<HH;++h){ const float v=s_high[t][h]; n2=fmaf(v,v,n2); }
    const float n=sqrtf(n2), ne=fmaxf(n,1e-7f), sq=ne*ne;
    float sc=sq/((1.0f+sq)*ne);
    if (t>=ka) sc=0.f;
    s_scale[t]=sc;
  }
  __syncthreads();
  {
    const int w2=t>>6, lane=t&63;
    const float sc=s_scale[w2];
    float* ob=out+(size_t)b*(KMAX*HH);
    ob[w2*HH+lane]=s_high[w2][lane]*sc;
    ob[w2*HH+lane+64]=s_high[w2][lane+64]*sc;
    ob[KE*HH+t]=0.0f; ob[KE*HH+512+t]=0.0f;
    if (t<KMAX) {
      float* om=out+(size_t)NB*KMAX*HH;
      om[b*KMAX+t]=(t<ka)?1.0f:0.0f;
    }
  }
}

extern "C" void kernel_launch(void* const* d_in, const int* in_sizes, int n_in,
                              void* d_out, int out_size, void* d_ws, size_t ws_size,
                              hipStream_t stream) {
  const float* inputs  = (const float*)d_in[0];
  const int*   seq_len = (const int*)d_in[1];
  const float* Wm      = (const float*)d_in[2];
  const float* r_init  = (const float*)d_in[3];
  float* out           = (float*)d_out;
  const size_t wt_bytes = (size_t)HH * LL * sizeof(u16);   // 64 KB each
  if (ws_size >= 2 * wt_bytes) {
    u16* wt_hi = (u16*)d_ws;
    u16* wt_lo = wt_hi + (size_t)HH * LL;
    hipLaunchKernelGGL(prep_w, dim3(128), dim3(256), 0, stream, Wm, wt_hi, wt_lo);
    hipLaunchKernelGGL(capsule_one, dim3(NB), dim3(512), 0, stream,
                       inputs, seq_len, wt_hi, wt_lo, r_init, out);
  } else {
    hipLaunchKernelGGL(capsule_fused, dim3(NB), dim3(512), 0, stream,
                       inputs, seq_len, Wm, r_init, out);
  }
}